// Round 8
// baseline (506.414 us; speedup 1.0000x reference)
//
#include <hip/hip_runtime.h>
#include <hip/hip_bf16.h>

#define NN 100000
#define NE 1000000
#define NTILES 98   // ceil(NN/1024)
#define BSHIFT 13          // bucket = row >> 13 (8192 nodes/bucket)
#define NB 13              // ceil(100000/8192)
#define CAP 98304          // bucket capacity (expected 81920, +60 sigma)
#define BPB (CAP/256)      // 384 blocks per bucket in scat_k

// ============ edge_index dtype probe (int32 vs int64 storage) ============
__global__ void probe_i_k(const unsigned long long* __restrict__ ei, int* __restrict__ mode64){
  __shared__ int big;
  if(threadIdx.x==0) big=0;
  __syncthreads();
  int t = threadIdx.x;
  for(int i=0;i<16;i++){
    long idx = (long)(t*16+i) * (NE/4096);
    if(ei[idx] >> 32) big = 1;
  }
  __syncthreads();
  if(t==0) *mode64 = big ? 0 : 1;
}

__device__ __forceinline__ int load_idx(const void* ei, long e, int m64){
  return m64 ? (int)((const long long*)ei)[e] : ((const int*)ei)[e];
}

// ================= CSR build (two-phase binned scatter) =================
// R7 post-mortem: direct scatter fill_k had WRITE_SIZE=65MB for 8MB payload
// (64B-line write amplification on random 8B stores) at ~0.9 TB/s -> 75 us.
// Phase A bins edges into 13 row-range buckets (chunked, ~coalesced writes,
// folds in degree histogram); phase B scatters bucket-by-bucket so each
// bucket's 0.8MB CSR slice stays L2-resident and lines absorb all sub-writes.

__global__ void init_k(int* __restrict__ deg, int* __restrict__ gcur){
  int i = blockIdx.x*256 + threadIdx.x;
  if(i<NN) deg[i]=0;
  if(i<16) gcur[i]=i*CAP;
}

__global__ __launch_bounds__(256) void bin_k(const void* __restrict__ ei,
    const int* __restrict__ mode, const float* __restrict__ ew,
    int* __restrict__ deg, int* __restrict__ gcur, int4* __restrict__ blist){
  __shared__ int cnt[16];
  __shared__ int basep[16];
  int tid = threadIdx.x;
  if(tid<16) cnt[tid]=0;
  __syncthreads();
  int e = blockIdx.x*256 + tid;
  int m64 = *mode;
  int r=0, c=0, b=0; float wv=0.f;
  bool valid = (e < NE);
  if(valid){
    r  = load_idx(ei, e,          m64);
    c  = load_idx(ei, (long)NE+e, m64);
    wv = ew[e];
    b  = r >> BSHIFT;
    atomicAdd(&cnt[b], 1);
    atomicAdd(&deg[r], 1);
  }
  __syncthreads();
  if(tid<16){
    basep[tid] = cnt[tid] ? atomicAdd(&gcur[tid], cnt[tid]) : 0;
    cnt[tid] = 0;
  }
  __syncthreads();
  if(valid){
    int rank = atomicAdd(&cnt[b], 1);
    blist[basep[b] + rank] = make_int4(r, c, __float_as_int(wv), 0);
  }
}

__global__ __launch_bounds__(256) void scat_k(const int4* __restrict__ blist,
    const int* __restrict__ gcur, int* __restrict__ cursor, int2* __restrict__ csr_cw){
  int b     = blockIdx.x / BPB;
  int local = blockIdx.x - b*BPB;
  int idx   = local*256 + threadIdx.x;
  int cnt   = gcur[b] - b*CAP;
  if(idx >= cnt) return;
  int4 rec = blist[(long)b*CAP + idx];
  int slot = atomicAdd(&cursor[rec.x], 1);
  csr_cw[slot] = make_int2(rec.y, rec.z);
}

__global__ void scan_tiles_k(const int* __restrict__ deg, int* __restrict__ partial,
                             int* __restrict__ tileSums){
  __shared__ int lds[256];
  int t = threadIdx.x;
  int base = blockIdx.x*1024 + t*4;
  int v0 = (base+0<NN)?deg[base+0]:0;
  int v1 = (base+1<NN)?deg[base+1]:0;
  int v2 = (base+2<NN)?deg[base+2]:0;
  int v3 = (base+3<NN)?deg[base+3]:0;
  int s = v0+v1+v2+v3;
  lds[t]=s; __syncthreads();
  for(int off=1; off<256; off<<=1){
    int x = (t>=off)? lds[t-off]:0;
    __syncthreads();
    lds[t]+=x;
    __syncthreads();
  }
  int excl = lds[t]-s;
  if(t==255) tileSums[blockIdx.x]=lds[255];
  if(base+0<NN) partial[base+0]=excl;
  if(base+1<NN) partial[base+1]=excl+v0;
  if(base+2<NN) partial[base+2]=excl+v0+v1;
  if(base+3<NN) partial[base+3]=excl+v0+v1+v2;
}

__global__ void scan_top_k(const int* __restrict__ tileSums, int* __restrict__ tileOff){
  if(threadIdx.x==0){
    int acc=0;
    for(int b=0;b<NTILES;b++){ tileOff[b]=acc; acc+=tileSums[b]; }
  }
}

__global__ void scan_add_k(const int* __restrict__ partial, const int* __restrict__ tileOff,
                           int* __restrict__ offsets, int* __restrict__ cursor){
  int i = blockIdx.x*256+threadIdx.x;
  if(i<NN){ int o = partial[i]+tileOff[i>>10]; offsets[i]=o; cursor[i]=o; }
  if(i==0) offsets[NN]=NE;
}

// ============ input projection: h = x @ Wp^T + bp ============

__global__ void proj_k(const float* __restrict__ x, const float* __restrict__ Wp,
                       const float* __restrict__ bp, float* __restrict__ h){
  int tid = blockIdx.x*256+threadIdx.x;
  int n = tid>>6, j = tid&63;
  if(n>=NN) return;
  float acc = bp[j];
  #pragma unroll
  for(int k=0;k<8;k++) acc += x[n*8+k]*Wp[j*8+k];
  h[(long)n*64+j]=acc;
}

// ========== dual GEMM: h_self = h@Ws^T+bs, h_neigh = h@Wn^T+bn ==========
// R5 lesson: full unroll -> VGPR=256 + scratch spill (1.9GB HBM). Keep unroll 2
// + launch_bounds(256,3) (3 blocks/CU LDS cap).

__global__ __launch_bounds__(256, 3) void gemm_k(const float* __restrict__ h,
    const float* __restrict__ Ws, const float* __restrict__ bs,
    const float* __restrict__ Wn, const float* __restrict__ bn,
    float* __restrict__ hs, float* __restrict__ hn){
  __shared__ float sh[64][68];
  __shared__ float sws[64*64];
  __shared__ float swn[64*64];
  int tid = threadIdx.x;
  int n0 = blockIdx.x*64;
  {
    int r = tid>>2, q = tid&3;
    int off = 4*((r>>2)&7);
    #pragma unroll
    for(int i=0;i<4;i++){
      int col = q*16 + i*4;
      float4 hv = make_float4(0.f,0.f,0.f,0.f);
      if(n0+r<NN) hv = *(const float4*)(h + (long)(n0+r)*64 + col);
      *(float4*)&sh[r][col] = hv;
      int scol = col ^ off;
      *(float4*)&sws[r*64+scol] = *(const float4*)(Ws + r*64 + col);
      *(float4*)&swn[r*64+scol] = *(const float4*)(Wn + r*64 + col);
    }
  }
  __syncthreads();
  int ty = tid>>4, tx = tid&15;
  float accs[4][4]={{0.f}}, accn[4][4]={{0.f}};
  int woff = 4*(tx&7);
  #pragma unroll 2
  for(int k=0;k<64;k+=4){
    float4 hv[4];
    #pragma unroll
    for(int m=0;m<4;m++) hv[m] = *(float4*)&sh[ty*4+m][k];
    int sk = k ^ woff;
    #pragma unroll
    for(int c=0;c<4;c++){
      float4 w1 = *(float4*)&sws[(tx*4+c)*64 + sk];
      float4 w2 = *(float4*)&swn[(tx*4+c)*64 + sk];
      #pragma unroll
      for(int m=0;m<4;m++){
        accs[m][c] += hv[m].x*w1.x + hv[m].y*w1.y + hv[m].z*w1.z + hv[m].w*w1.w;
        accn[m][c] += hv[m].x*w2.x + hv[m].y*w2.y + hv[m].z*w2.z + hv[m].w*w2.w;
      }
    }
  }
  float4 bsv = *(const float4*)(bs + tx*4);
  float4 bnv = *(const float4*)(bn + tx*4);
  const float* bsp = (const float*)&bsv;
  const float* bnp = (const float*)&bnv;
  #pragma unroll
  for(int m=0;m<4;m++){
    int n = n0 + ty*4 + m;
    if(n>=NN) continue;
    float4 o1, o2;
    float* p1=(float*)&o1; float* p2=(float*)&o2;
    #pragma unroll
    for(int c=0;c<4;c++){ p1[c]=accs[m][c]+bsp[c]; p2[c]=accn[m][c]+bnp[c]; }
    *(float4*)(hs + (long)n*64 + tx*4) = o1;
    *(float4*)(hn + (long)n*64 + tx*4) = o2;
  }
}

// ========== fused aggregate + LN + leaky + residual ==========
// R6: coalesced int2 metadata load + __shfl broadcast; hn gathers
// address-independent, unrolled x4 -> 4 loads in flight per wave.

__global__ __launch_bounds__(256) void agg_k(
    const float* __restrict__ h, const float* __restrict__ hs, const float* __restrict__ hn,
    const int* __restrict__ offsets, const int2* __restrict__ csr_cw,
    const float* __restrict__ Wedge, const float* __restrict__ gamma, const float* __restrict__ beta,
    float* __restrict__ h_out){
  int wid = (blockIdx.x*256 + threadIdx.x) >> 6;
  int lane = threadIdx.x & 63;
  if(wid >= NN) return;
  int n = wid;
  float we = Wedge[lane];
  int s = __builtin_amdgcn_readfirstlane(offsets[n]);
  int e = __builtin_amdgcn_readfirstlane(offsets[n+1]);
  float acc = 0.f;
  for(int base = s; base < e; base += 64){
    int m = e - base; if(m > 64) m = 64;
    int2 cw = make_int2(0, 0);
    if(lane < m) cw = csr_cw[base + lane];
    int   myc = cw.x;
    float myw = __int_as_float(cw.y);
    int j = 0;
    for(; j + 4 <= m; j += 4){
      int   c0 = __shfl(myc, j+0, 64); float w0 = __shfl(myw, j+0, 64);
      int   c1 = __shfl(myc, j+1, 64); float w1 = __shfl(myw, j+1, 64);
      int   c2 = __shfl(myc, j+2, 64); float w2 = __shfl(myw, j+2, 64);
      int   c3 = __shfl(myc, j+3, 64); float w3 = __shfl(myw, j+3, 64);
      float v0 = hn[(long)c0*64 + lane];
      float v1 = hn[(long)c1*64 + lane];
      float v2 = hn[(long)c2*64 + lane];
      float v3 = hn[(long)c3*64 + lane];
      float g0 = 1.0f/(1.0f + __expf(-w0*we));
      float g1 = 1.0f/(1.0f + __expf(-w1*we));
      float g2 = 1.0f/(1.0f + __expf(-w2*we));
      float g3 = 1.0f/(1.0f + __expf(-w3*we));
      acc += v0*g0; acc += v1*g1; acc += v2*g2; acc += v3*g3;
    }
    for(; j < m; ++j){
      int   c  = __shfl(myc, j, 64);
      float wv = __shfl(myw, j, 64);
      float g  = 1.0f/(1.0f + __expf(-wv*we));
      acc += hn[(long)c*64 + lane] * g;
    }
  }
  float v = hs[(long)n*64+lane] + acc;
  float sum = v, sumsq = v*v;
  #pragma unroll
  for(int off=32; off; off>>=1){
    sum   += __shfl_xor(sum,   off, 64);
    sumsq += __shfl_xor(sumsq, off, 64);
  }
  float mu  = sum * (1.f/64.f);
  float var = sumsq * (1.f/64.f) - mu*mu;
  float o = (v - mu) * rsqrtf(var + 1e-5f) * gamma[lane] + beta[lane];
  o = (o >= 0.f) ? o : 0.2f*o;
  h_out[(long)n*64+lane] = h[(long)n*64+lane] + o;
}

// ================= host launch =================

static inline char* align256(char* p){
  return (char*)(((uintptr_t)p + 255) & ~(uintptr_t)255);
}

extern "C" void kernel_launch(void* const* d_in, const int* in_sizes, int n_in,
                              void* d_out, int out_size, void* d_ws, size_t ws_size,
                              hipStream_t stream) {
  const float* x      = (const float*)d_in[0];
  const void*  ei     = d_in[1];                 // [2, NE], int32 (probed vs int64)
  const float* ew     = (const float*)d_in[2];
  const float* Wp     = (const float*)d_in[3];
  const float* bp     = (const float*)d_in[4];
  const float* Wself  = (const float*)d_in[5];
  const float* bself  = (const float*)d_in[6];
  const float* Wneigh = (const float*)d_in[7];
  const float* bneigh = (const float*)d_in[8];
  const float* Wedge  = (const float*)d_in[9];
  const float* gamma  = (const float*)d_in[10];
  const float* beta   = (const float*)d_in[11];
  float* out          = (float*)d_out;           // fp32 output (reference dtype)

  char* w = (char*)d_ws;
  float* h       = (float*)w;  w = align256(w + (size_t)NN*64*4);
  float* hs      = (float*)w;  w = align256(w + (size_t)NN*64*4);
  float* hnb     = (float*)w;  w = align256(w + (size_t)NN*64*4);
  int*   deg     = (int*)w;    w = align256(w + (size_t)NN*4);
  int*   partial = (int*)w;    w = align256(w + (size_t)NN*4);
  int*   tileSum = (int*)w;    w = align256(w + (size_t)NTILES*4);
  int*   tileOff = (int*)w;    w = align256(w + (size_t)NTILES*4);
  int*   offsets = (int*)w;    w = align256(w + (size_t)(NN+1)*4);
  int*   cursor  = (int*)w;    w = align256(w + (size_t)NN*4);
  int*   mode64  = (int*)w;    w = align256(w + 4);
  int*   gcur    = (int*)w;    w = align256(w + 16*4);
  int2*  csr_cw  = (int2*)w;   w = align256(w + (size_t)NE*8);
  // bucket list aliases hs+hnb (dead until first gemm_k, which runs after scat_k)
  int4*  blist   = (int4*)hs;  // 13*98304*16B = 20.4 MB <= 51.2 MB

  probe_i_k<<<1, 256, 0, stream>>>((const unsigned long long*)ei, mode64);

  init_k<<<(NN+255)/256, 256, 0, stream>>>(deg, gcur);
  bin_k<<<(NE+255)/256, 256, 0, stream>>>(ei, mode64, ew, deg, gcur, blist);
  scan_tiles_k<<<NTILES, 256, 0, stream>>>(deg, partial, tileSum);
  scan_top_k<<<1, 64, 0, stream>>>(tileSum, tileOff);
  scan_add_k<<<(NN+255)/256, 256, 0, stream>>>(partial, tileOff, offsets, cursor);
  scat_k<<<NB*BPB, 256, 0, stream>>>(blist, gcur, cursor, csr_cw);

  proj_k<<<(NN*64+255)/256, 256, 0, stream>>>(x, Wp, bp, h);

  const int gemmBlocks = (NN + 63)/64;
  const int aggBlocks  = (NN*64 + 255)/256;
  for(int l=0; l<3; ++l){
    gemm_k<<<gemmBlocks, 256, 0, stream>>>(h, Wself + (size_t)l*64*64, bself + l*64,
                                           Wneigh + (size_t)l*64*64, bneigh + l*64, hs, hnb);
    float* dst = (l < 2) ? h : out;
    agg_k<<<aggBlocks, 256, 0, stream>>>(h, hs, hnb, offsets, csr_cw,
                                         Wedge + l*64, gamma + l*64, beta + l*64, dst);
  }
}

// Round 10
// 495.268 us; speedup vs baseline: 1.0225x; 1.0225x over previous
//
#include <hip/hip_runtime.h>
#include <hip/hip_bf16.h>

#define NN 100000
#define NE 1000000
#define NTILES 98   // ceil(NN/1024)

// f32 -> bf16 bits, round-to-nearest-even (no .data member on this ROCm)
__device__ __forceinline__ unsigned short f32_to_bf16_bits(float f){
  unsigned u = __float_as_uint(f);
  u += 0x7FFFu + ((u >> 16) & 1u);
  return (unsigned short)(u >> 16);
}

// ============ edge_index dtype probe (int32 vs int64 storage) ============
__global__ void probe_i_k(const unsigned long long* __restrict__ ei, int* __restrict__ mode64){
  __shared__ int big;
  if(threadIdx.x==0) big=0;
  __syncthreads();
  int t = threadIdx.x;
  for(int i=0;i<16;i++){
    long idx = (long)(t*16+i) * (NE/4096);
    if(ei[idx] >> 32) big = 1;
  }
  __syncthreads();
  if(t==0) *mode64 = big ? 0 : 1;
}

__device__ __forceinline__ int load_idx(const void* ei, long e, int m64){
  return m64 ? (int)((const long long*)ei)[e] : ((const int*)ei)[e];
}

// ================= CSR build (single-phase scatter) =================
// R8 lesson: two-phase binning loses (concurrent blocks defeat bucket-major
// L2 blocking); 1M random-line scatter has ~64MB writeback floor. Keep simple.

__global__ void zero_i32_k(int* __restrict__ p, int n){
  int i = blockIdx.x*256 + threadIdx.x;
  if(i<n) p[i]=0;
}

__global__ void hist_k(const void* __restrict__ ei, const int* __restrict__ mode,
                       int* __restrict__ deg){
  int e = blockIdx.x*256 + threadIdx.x;
  int m64 = *mode;
  if(e<NE) atomicAdd(&deg[load_idx(ei, e, m64)], 1);
}

__global__ void scan_tiles_k(const int* __restrict__ deg, int* __restrict__ partial,
                             int* __restrict__ tileSums){
  __shared__ int lds[256];
  int t = threadIdx.x;
  int base = blockIdx.x*1024 + t*4;
  int v0 = (base+0<NN)?deg[base+0]:0;
  int v1 = (base+1<NN)?deg[base+1]:0;
  int v2 = (base+2<NN)?deg[base+2]:0;
  int v3 = (base+3<NN)?deg[base+3]:0;
  int s = v0+v1+v2+v3;
  lds[t]=s; __syncthreads();
  for(int off=1; off<256; off<<=1){
    int x = (t>=off)? lds[t-off]:0;
    __syncthreads();
    lds[t]+=x;
    __syncthreads();
  }
  int excl = lds[t]-s;
  if(t==255) tileSums[blockIdx.x]=lds[255];
  if(base+0<NN) partial[base+0]=excl;
  if(base+1<NN) partial[base+1]=excl+v0;
  if(base+2<NN) partial[base+2]=excl+v0+v1;
  if(base+3<NN) partial[base+3]=excl+v0+v1+v2;
}

__global__ void scan_top_k(const int* __restrict__ tileSums, int* __restrict__ tileOff){
  if(threadIdx.x==0){
    int acc=0;
    for(int b=0;b<NTILES;b++){ tileOff[b]=acc; acc+=tileSums[b]; }
  }
}

__global__ void scan_add_k(const int* __restrict__ partial, const int* __restrict__ tileOff,
                           int* __restrict__ offsets, int* __restrict__ cursor){
  int i = blockIdx.x*256+threadIdx.x;
  if(i<NN){ int o = partial[i]+tileOff[i>>10]; offsets[i]=o; cursor[i]=o; }
  if(i==0) offsets[NN]=NE;
}

// packed CSR payload: .x = col, .y = edge weight bits
__global__ void fill_k(const void* __restrict__ ei, const int* __restrict__ mode,
                       const float* __restrict__ ew, int* __restrict__ cursor,
                       int2* __restrict__ csr_cw){
  int e = blockIdx.x*256+threadIdx.x;
  int m64 = *mode;
  if(e<NE){
    int r = load_idx(ei, e,          m64);
    int c = load_idx(ei, (long)NE+e, m64);
    int slot = atomicAdd(&cursor[r],1);
    csr_cw[slot] = make_int2(c, __float_as_int(ew[e]));
  }
}

// ============ input projection: h = x @ Wp^T + bp ============

__global__ void proj_k(const float* __restrict__ x, const float* __restrict__ Wp,
                       const float* __restrict__ bp, float* __restrict__ h){
  int tid = blockIdx.x*256+threadIdx.x;
  int n = tid>>6, j = tid&63;
  if(n>=NN) return;
  float acc = bp[j];
  #pragma unroll
  for(int k=0;k<8;k++) acc += x[n*8+k]*Wp[j*8+k];
  h[(long)n*64+j]=acc;
}

// ========== dual GEMM: h_self = h@Ws^T+bs (fp32), h_neigh -> bf16 ==========
// R5 lesson: full unroll -> VGPR=256 + scratch spill. Keep unroll 2 +
// launch_bounds(256,3). R9: hn's only consumer is agg_k's random gather ->
// emit hn in bf16 (halves gather bytes + hn footprint 25.6->12.8MB).

__global__ __launch_bounds__(256, 3) void gemm_k(const float* __restrict__ h,
    const float* __restrict__ Ws, const float* __restrict__ bs,
    const float* __restrict__ Wn, const float* __restrict__ bn,
    float* __restrict__ hs, unsigned short* __restrict__ hnb){
  __shared__ float sh[64][68];
  __shared__ float sws[64*64];
  __shared__ float swn[64*64];
  int tid = threadIdx.x;
  int n0 = blockIdx.x*64;
  {
    int r = tid>>2, q = tid&3;
    int off = 4*((r>>2)&7);
    #pragma unroll
    for(int i=0;i<4;i++){
      int col = q*16 + i*4;
      float4 hv = make_float4(0.f,0.f,0.f,0.f);
      if(n0+r<NN) hv = *(const float4*)(h + (long)(n0+r)*64 + col);
      *(float4*)&sh[r][col] = hv;
      int scol = col ^ off;
      *(float4*)&sws[r*64+scol] = *(const float4*)(Ws + r*64 + col);
      *(float4*)&swn[r*64+scol] = *(const float4*)(Wn + r*64 + col);
    }
  }
  __syncthreads();
  int ty = tid>>4, tx = tid&15;
  float accs[4][4]={{0.f}}, accn[4][4]={{0.f}};
  int woff = 4*(tx&7);
  #pragma unroll 2
  for(int k=0;k<64;k+=4){
    float4 hv[4];
    #pragma unroll
    for(int m=0;m<4;m++) hv[m] = *(float4*)&sh[ty*4+m][k];
    int sk = k ^ woff;
    #pragma unroll
    for(int c=0;c<4;c++){
      float4 w1 = *(float4*)&sws[(tx*4+c)*64 + sk];
      float4 w2 = *(float4*)&swn[(tx*4+c)*64 + sk];
      #pragma unroll
      for(int m=0;m<4;m++){
        accs[m][c] += hv[m].x*w1.x + hv[m].y*w1.y + hv[m].z*w1.z + hv[m].w*w1.w;
        accn[m][c] += hv[m].x*w2.x + hv[m].y*w2.y + hv[m].z*w2.z + hv[m].w*w2.w;
      }
    }
  }
  float4 bsv = *(const float4*)(bs + tx*4);
  float4 bnv = *(const float4*)(bn + tx*4);
  const float* bsp = (const float*)&bsv;
  const float* bnp = (const float*)&bnv;
  #pragma unroll
  for(int m=0;m<4;m++){
    int n = n0 + ty*4 + m;
    if(n>=NN) continue;
    float4 o1;
    float* p1=(float*)&o1;
    ushort4 o2;
    unsigned short* p2=(unsigned short*)&o2;
    #pragma unroll
    for(int c=0;c<4;c++){
      p1[c] = accs[m][c]+bsp[c];
      p2[c] = f32_to_bf16_bits(accn[m][c]+bnp[c]);
    }
    *(float4*)(hs + (long)n*64 + tx*4) = o1;
    *(ushort4*)(hnb + (long)n*64 + tx*4) = o2;
  }
}

// ========== fused aggregate + LN + leaky + residual ==========
// R6: coalesced int2 metadata load + __shfl broadcast; hn gathers
// address-independent, unrolled x4 -> 4 loads in flight per wave.
// R9: hn gathered as bf16 bits (128B rows), accumulated fp32.

__global__ __launch_bounds__(256) void agg_k(
    const float* __restrict__ h, const float* __restrict__ hs,
    const unsigned short* __restrict__ hb,
    const int* __restrict__ offsets, const int2* __restrict__ csr_cw,
    const float* __restrict__ Wedge, const float* __restrict__ gamma, const float* __restrict__ beta,
    float* __restrict__ h_out){
  int wid = (blockIdx.x*256 + threadIdx.x) >> 6;
  int lane = threadIdx.x & 63;
  if(wid >= NN) return;
  int n = wid;
  float we = Wedge[lane];
  int s = __builtin_amdgcn_readfirstlane(offsets[n]);
  int e = __builtin_amdgcn_readfirstlane(offsets[n+1]);
  float acc = 0.f;
  for(int base = s; base < e; base += 64){
    int m = e - base; if(m > 64) m = 64;
    int2 cw = make_int2(0, 0);
    if(lane < m) cw = csr_cw[base + lane];
    int   myc = cw.x;
    float myw = __int_as_float(cw.y);
    int j = 0;
    for(; j + 4 <= m; j += 4){
      int   c0 = __shfl(myc, j+0, 64); float w0 = __shfl(myw, j+0, 64);
      int   c1 = __shfl(myc, j+1, 64); float w1 = __shfl(myw, j+1, 64);
      int   c2 = __shfl(myc, j+2, 64); float w2 = __shfl(myw, j+2, 64);
      int   c3 = __shfl(myc, j+3, 64); float w3 = __shfl(myw, j+3, 64);
      unsigned short u0 = hb[(long)c0*64 + lane];
      unsigned short u1 = hb[(long)c1*64 + lane];
      unsigned short u2 = hb[(long)c2*64 + lane];
      unsigned short u3 = hb[(long)c3*64 + lane];
      float v0 = __uint_as_float((unsigned)u0 << 16);
      float v1 = __uint_as_float((unsigned)u1 << 16);
      float v2 = __uint_as_float((unsigned)u2 << 16);
      float v3 = __uint_as_float((unsigned)u3 << 16);
      float g0 = 1.0f/(1.0f + __expf(-w0*we));
      float g1 = 1.0f/(1.0f + __expf(-w1*we));
      float g2 = 1.0f/(1.0f + __expf(-w2*we));
      float g3 = 1.0f/(1.0f + __expf(-w3*we));
      acc += v0*g0; acc += v1*g1; acc += v2*g2; acc += v3*g3;
    }
    for(; j < m; ++j){
      int   c  = __shfl(myc, j, 64);
      float wv = __shfl(myw, j, 64);
      float g  = 1.0f/(1.0f + __expf(-wv*we));
      float v  = __uint_as_float((unsigned)hb[(long)c*64 + lane] << 16);
      acc += v * g;
    }
  }
  float v = hs[(long)n*64+lane] + acc;
  float sum = v, sumsq = v*v;
  #pragma unroll
  for(int off=32; off; off>>=1){
    sum   += __shfl_xor(sum,   off, 64);
    sumsq += __shfl_xor(sumsq, off, 64);
  }
  float mu  = sum * (1.f/64.f);
  float var = sumsq * (1.f/64.f) - mu*mu;
  float o = (v - mu) * rsqrtf(var + 1e-5f) * gamma[lane] + beta[lane];
  o = (o >= 0.f) ? o : 0.2f*o;
  h_out[(long)n*64+lane] = h[(long)n*64+lane] + o;
}

// ================= host launch =================

static inline char* align256(char* p){
  return (char*)(((uintptr_t)p + 255) & ~(uintptr_t)255);
}

extern "C" void kernel_launch(void* const* d_in, const int* in_sizes, int n_in,
                              void* d_out, int out_size, void* d_ws, size_t ws_size,
                              hipStream_t stream) {
  const float* x      = (const float*)d_in[0];
  const void*  ei     = d_in[1];                 // [2, NE], int32 (probed vs int64)
  const float* ew     = (const float*)d_in[2];
  const float* Wp     = (const float*)d_in[3];
  const float* bp     = (const float*)d_in[4];
  const float* Wself  = (const float*)d_in[5];
  const float* bself  = (const float*)d_in[6];
  const float* Wneigh = (const float*)d_in[7];
  const float* bneigh = (const float*)d_in[8];
  const float* Wedge  = (const float*)d_in[9];
  const float* gamma  = (const float*)d_in[10];
  const float* beta   = (const float*)d_in[11];
  float* out          = (float*)d_out;           // fp32 output (reference dtype)

  char* w = (char*)d_ws;
  float* h        = (float*)w;  w = align256(w + (size_t)NN*64*4);
  float* hs       = (float*)w;  w = align256(w + (size_t)NN*64*4);
  unsigned short* hnb = (unsigned short*)w;  w = align256(w + (size_t)NN*64*2);
  int*   deg      = (int*)w;    w = align256(w + (size_t)NN*4);
  int*   partial  = (int*)w;    w = align256(w + (size_t)NN*4);
  int*   tileSum  = (int*)w;    w = align256(w + (size_t)NTILES*4);
  int*   tileOff  = (int*)w;    w = align256(w + (size_t)NTILES*4);
  int*   offsets  = (int*)w;    w = align256(w + (size_t)(NN+1)*4);
  int*   cursor   = (int*)w;    w = align256(w + (size_t)NN*4);
  int*   mode64   = (int*)w;    w = align256(w + 4);
  int2*  csr_cw   = (int2*)w;   w = align256(w + (size_t)NE*8);

  probe_i_k<<<1, 256, 0, stream>>>((const unsigned long long*)ei, mode64);

  zero_i32_k<<<(NN+255)/256, 256, 0, stream>>>(deg, NN);
  hist_k<<<(NE+255)/256, 256, 0, stream>>>(ei, mode64, deg);
  scan_tiles_k<<<NTILES, 256, 0, stream>>>(deg, partial, tileSum);
  scan_top_k<<<1, 64, 0, stream>>>(tileSum, tileOff);
  scan_add_k<<<(NN+255)/256, 256, 0, stream>>>(partial, tileOff, offsets, cursor);
  fill_k<<<(NE+255)/256, 256, 0, stream>>>(ei, mode64, ew, cursor, csr_cw);

  proj_k<<<(NN*64+255)/256, 256, 0, stream>>>(x, Wp, bp, h);

  const int gemmBlocks = (NN + 63)/64;
  const int aggBlocks  = (NN*64 + 255)/256;
  for(int l=0; l<3; ++l){
    gemm_k<<<gemmBlocks, 256, 0, stream>>>(h, Wself + (size_t)l*64*64, bself + l*64,
                                           Wneigh + (size_t)l*64*64, bneigh + l*64, hs, hnb);
    float* dst = (l < 2) ? h : out;
    agg_k<<<aggBlocks, 256, 0, stream>>>(h, hs, hnb, offsets, csr_cw,
                                         Wedge + l*64, gamma + l*64, beta + l*64, dst);
  }
}